// Round 3
// baseline (719.716 us; speedup 1.0000x reference)
//
#include <hip/hip_runtime.h>

#define CH      128
#define RBFD    200
#define NNODES  50000
#define NEDGES  600000
#define LOG2F_  0.6931471805599453f

// K padded to 224 for GEMM1 (7 k-tiles of 32); LDS row strides padded for banks
#define K1P     224
#define RSTR    232     // rbf_s row stride in bf16 elems (464 B -> 20 banks mod 32 -> 2-way, free)
#define HSTR    136     // h_s / w_s row stride in bf16 elems (272 B -> 4 banks mod 32 -> 2-way, free)

typedef __attribute__((ext_vector_type(8))) __bf16 bf16x8;
typedef __attribute__((ext_vector_type(4))) float  f32x4;

__device__ __forceinline__ float ssp(float x) {
    float sp = (x < 14.0f) ? __logf(1.0f + __expf(x)) : x;
    return sp - LOG2F_;
}

__device__ __forceinline__ unsigned short f2bf(float f) {
    union { float f; unsigned int u; } v; v.f = f;
    unsigned int r = v.u + 0x7FFFu + ((v.u >> 16) & 1u);   // RNE (finite inputs)
    return (unsigned short)(r >> 16);
}

__device__ __forceinline__ float bf2f(unsigned short s) {
    union { unsigned int u; float f; } v; v.u = ((unsigned int)s) << 16;
    return v.f;
}

// ---- prep: bf16-transposed weights  w1T[128][224] (zero-padded), w2T[128][128] ----
__global__ __launch_bounds__(256) void prep_weights(const float* __restrict__ w1,
                                                    const float* __restrict__ w2,
                                                    unsigned short* __restrict__ w1T,
                                                    unsigned short* __restrict__ w2T) {
    int i = blockIdx.x * 256 + threadIdx.x;
    if (i < 128 * K1P) {
        int n = i / K1P, k = i % K1P;
        w1T[i] = (k < RBFD) ? f2bf(w1[k * CH + n]) : (unsigned short)0;
    } else {
        int j = i - 128 * K1P;
        if (j < 128 * 128) {
            int n = j / 128, k = j % 128;
            w2T[j] = f2bf(w2[k * CH + n]);
        }
    }
}

// ---- CSR build ----
__global__ __launch_bounds__(256) void k_hist(const int* __restrict__ src, int* __restrict__ cur) {
    int e = blockIdx.x * 256 + threadIdx.x;
    if (e < NEDGES) atomicAdd(&cur[src[e]], 1);
}

__global__ __launch_bounds__(256) void k_scan(int* __restrict__ cur,          // in: deg, out: cursor
                                              int* __restrict__ csr_off) {    // out: [N+1]
    __shared__ int ps[256];
    const int t = threadIdx.x;
    const int chunk = (NNODES + 255) / 256;           // 196
    const int lo = t * chunk, hi = min(lo + chunk, NNODES);
    int s = 0;
    for (int i = lo; i < hi; i++) s += cur[i];
    ps[t] = s;
    __syncthreads();
    for (int d = 1; d < 256; d <<= 1) {
        int v = (t >= d) ? ps[t - d] : 0;
        __syncthreads();
        ps[t] += v;
        __syncthreads();
    }
    int run = (t == 0) ? 0 : ps[t - 1];
    for (int i = lo; i < hi; i++) {
        int dg = cur[i];
        csr_off[i] = run;
        cur[i] = run;
        run += dg;
    }
    if (t == 255) csr_off[NNODES] = run;
}

__global__ __launch_bounds__(256) void k_fill(const int* __restrict__ src,
                                              int* __restrict__ cur,
                                              int* __restrict__ eidx) {
    int e = blockIdx.x * 256 + threadIdx.x;
    if (e < NEDGES) {
        int pos = atomicAdd(&cur[src[e]], 1);
        eidx[pos] = e;
    }
}

// ---- edge pipeline: w = ssp(ssp(rbf@w1+b1)@w2+b2)
//      MODE 0: streaming write to wbuf[E][128] bf16 (gather path)
//      MODE 1: atomicAdd into convw[src]          (fallback path) ----
template <int MODE>
__global__ __launch_bounds__(256, 3) void edge_kernel(const float* __restrict__ rbf,
                                                      const float* __restrict__ b1,
                                                      const float* __restrict__ b2,
                                                      const int* __restrict__ src,
                                                      const unsigned short* __restrict__ w1T,
                                                      const unsigned short* __restrict__ w2T,
                                                      unsigned short* __restrict__ wbuf,
                                                      float* __restrict__ convw) {
    __shared__ unsigned short rbf_s[64 * RSTR];   // 29696 B; reused as w_s after GEMM1
    __shared__ unsigned short h_s[64 * HSTR];     // 17408 B
    unsigned short* w_s = rbf_s;                  // [64][HSTR] alias (dead after GEMM1)
    const int t = threadIdx.x;
    const int lane = t & 63;
    const int wv = t >> 6;
    const size_t e0 = (size_t)blockIdx.x * 64;

    const int l15 = lane & 15;
    const int lg  = lane >> 4;
    const int col0 = wv * 32 + l15;

    // preload B1 fragments
    bf16x8 B1[2][7];
#pragma unroll
    for (int nt = 0; nt < 2; nt++) {
        const int row = wv * 32 + nt * 16 + l15;
#pragma unroll
        for (int kt = 0; kt < 7; kt++)
            B1[nt][kt] = *(const bf16x8*)(w1T + (size_t)row * K1P + kt * 32 + lg * 8);
    }

    // stage rbf tile [64][200] fp32 -> bf16 LDS, zero-pad k=200..231
    {
        const float4* g = (const float4*)(rbf + e0 * RBFD);
        for (int i = t; i < 3200; i += 256) {
            float4 v = g[i];
            int row = i / 50, c4 = (i % 50) * 4;
            unsigned short* d = &rbf_s[row * RSTR + c4];
            union { unsigned short s[4]; unsigned long long u; } p;
            p.s[0] = f2bf(v.x); p.s[1] = f2bf(v.y); p.s[2] = f2bf(v.z); p.s[3] = f2bf(v.w);
            *(unsigned long long*)d = p.u;
        }
        for (int i = t; i < 2048; i += 256) {
            int row = i >> 5, k = RBFD + (i & 31);
            rbf_s[row * RSTR + k] = 0;
        }
    }
    __syncthreads();

    const float bias10 = b1[col0];
    const float bias11 = b1[col0 + 16];

    // GEMM1: h = ssp(rbf @ w1 + b1) -> h_s
#pragma unroll
    for (int m = 0; m < 4; m++) {
        f32x4 acc0 = {0.f, 0.f, 0.f, 0.f};
        f32x4 acc1 = {0.f, 0.f, 0.f, 0.f};
        const unsigned short* abase = &rbf_s[(m * 16 + l15) * RSTR + lg * 8];
#pragma unroll
        for (int kt = 0; kt < 7; kt++) {
            bf16x8 a = *(const bf16x8*)(abase + kt * 32);
            acc0 = __builtin_amdgcn_mfma_f32_16x16x32_bf16(a, B1[0][kt], acc0, 0, 0, 0);
            acc1 = __builtin_amdgcn_mfma_f32_16x16x32_bf16(a, B1[1][kt], acc1, 0, 0, 0);
        }
        const int hrow0 = m * 16 + lg * 4;        // C/D: row=(lane>>4)*4+reg, col=lane&15
#pragma unroll
        for (int r = 0; r < 4; r++) {
            h_s[(hrow0 + r) * HSTR + col0]      = f2bf(ssp(acc0[r] + bias10));
            h_s[(hrow0 + r) * HSTR + col0 + 16] = f2bf(ssp(acc1[r] + bias11));
        }
    }
    __syncthreads();   // after this, rbf_s is dead -> reusable as w_s

    // preload B2 fragments
    bf16x8 B2[2][4];
#pragma unroll
    for (int nt = 0; nt < 2; nt++) {
        const int row = wv * 32 + nt * 16 + l15;
#pragma unroll
        for (int kt = 0; kt < 4; kt++)
            B2[nt][kt] = *(const bf16x8*)(w2T + (size_t)row * 128 + kt * 32 + lg * 8);
    }

    const float bias20 = b2[col0];
    const float bias21 = b2[col0 + 16];

    // GEMM2: w = ssp(h @ w2 + b2)
#pragma unroll
    for (int m = 0; m < 4; m++) {
        f32x4 acc0 = {0.f, 0.f, 0.f, 0.f};
        f32x4 acc1 = {0.f, 0.f, 0.f, 0.f};
        const unsigned short* abase = &h_s[(m * 16 + l15) * HSTR + lg * 8];
#pragma unroll
        for (int kt = 0; kt < 4; kt++) {
            bf16x8 a = *(const bf16x8*)(abase + kt * 32);
            acc0 = __builtin_amdgcn_mfma_f32_16x16x32_bf16(a, B2[0][kt], acc0, 0, 0, 0);
            acc1 = __builtin_amdgcn_mfma_f32_16x16x32_bf16(a, B2[1][kt], acc1, 0, 0, 0);
        }
        const int erow0 = m * 16 + lg * 4;
        if (MODE == 0) {
#pragma unroll
            for (int r = 0; r < 4; r++) {
                w_s[(erow0 + r) * HSTR + col0]      = f2bf(ssp(acc0[r] + bias20));
                w_s[(erow0 + r) * HSTR + col0 + 16] = f2bf(ssp(acc1[r] + bias21));
            }
        } else {
#pragma unroll
            for (int r = 0; r < 4; r++) {
                const int e = (int)e0 + erow0 + r;
                const int s = src[e];
                const size_t off = (size_t)s * CH;
                atomicAdd(&convw[off + col0],      ssp(acc0[r] + bias20));
                atomicAdd(&convw[off + col0 + 16], ssp(acc1[r] + bias21));
            }
        }
    }

    if (MODE == 0) {
        __syncthreads();
        // cooperative coalesced copy-out: 64 rows x 128 bf16 = 1024 float4
        for (int i = t; i < 1024; i += 256) {
            const int row = i >> 4, q = i & 15;
            float4 v = *(const float4*)&w_s[row * HSTR + q * 8];
            ((float4*)wbuf)[(e0 + row) * 16 + q] = v;
        }
    }
}

// ---- node side, gather path: f=x@w3; conv = f * segsum(wbuf); y=ssp(conv@w4+b4);
//      out = x + y@w5 + b5 ----
__global__ __launch_bounds__(256) void node_gather(const float* __restrict__ x,
                                                   const float* __restrict__ w3,
                                                   const float* __restrict__ w4,
                                                   const float* __restrict__ b4,
                                                   const float* __restrict__ w5,
                                                   const float* __restrict__ b5,
                                                   const unsigned short* __restrict__ wbuf,
                                                   const int* __restrict__ eidx,
                                                   const int* __restrict__ csr_off,
                                                   float* __restrict__ out,
                                                   int n_nodes) {
    __shared__ float A[32 * 128];
    __shared__ float B[32 * 128];
    const int t = threadIdx.x;
    const int n0 = blockIdx.x * 32;
    const int rows = min(32, n_nodes - n0);

    {   // stage x tile
        const float4* g = (const float4*)(x + (size_t)n0 * CH);
        float4* s = (float4*)A;
        for (int i = t; i < rows * 32; i += 256) s[i] = g[i];
    }
    __syncthreads();

    const int c = t & 127, eh = t >> 7;
    float acc[16];

    // f = x @ w3 -> B
#pragma unroll
    for (int i = 0; i < 16; i++) acc[i] = 0.f;
    for (int k = 0; k < 128; k += 4) {
        const float wa = w3[(k + 0) * CH + c];
        const float wb = w3[(k + 1) * CH + c];
        const float wc = w3[(k + 2) * CH + c];
        const float wd = w3[(k + 3) * CH + c];
#pragma unroll
        for (int i = 0; i < 16; i++) {
            const float4 v = *(const float4*)&A[(eh * 16 + i) * CH + k];
            acc[i] = fmaf(v.x, wa, acc[i]);
            acc[i] = fmaf(v.y, wb, acc[i]);
            acc[i] = fmaf(v.z, wc, acc[i]);
            acc[i] = fmaf(v.w, wd, acc[i]);
        }
    }
#pragma unroll
    for (int i = 0; i < 16; i++) B[(eh * 16 + i) * 128 + c] = acc[i];
    __syncthreads();

    // gather-sum: thread (c, eh) fully handles nodes [eh*16, eh*16+16)
    for (int i = 0; i < 16; i++) {
        const int r = eh * 16 + i;
        const int n = n0 + r;
        float conv = 0.f;
        if (n < n_nodes) {
            const int o0 = csr_off[n], o1 = csr_off[n + 1];
            float s0 = 0.f, s1 = 0.f;
            int j = o0;
            for (; j + 1 < o1; j += 2) {
                const int ea = eidx[j], eb = eidx[j + 1];
                s0 += bf2f(wbuf[(size_t)ea * CH + c]);
                s1 += bf2f(wbuf[(size_t)eb * CH + c]);
            }
            if (j < o1) s0 += bf2f(wbuf[(size_t)eidx[j] * CH + c]);
            conv = B[r * 128 + c] * (s0 + s1);
        }
        __syncthreads();          // all lanes: B read above, write below
        B[r * 128 + c] = conv;
    }
    __syncthreads();

    // y = ssp(B @ w4 + b4) -> A
#pragma unroll
    for (int i = 0; i < 16; i++) acc[i] = 0.f;
    for (int k = 0; k < 128; k += 4) {
        const float wa = w4[(k + 0) * CH + c];
        const float wb = w4[(k + 1) * CH + c];
        const float wc = w4[(k + 2) * CH + c];
        const float wd = w4[(k + 3) * CH + c];
#pragma unroll
        for (int i = 0; i < 16; i++) {
            const float4 v = *(const float4*)&B[(eh * 16 + i) * CH + k];
            acc[i] = fmaf(v.x, wa, acc[i]);
            acc[i] = fmaf(v.y, wb, acc[i]);
            acc[i] = fmaf(v.z, wc, acc[i]);
            acc[i] = fmaf(v.w, wd, acc[i]);
        }
    }
    {
        const float bias4 = b4[c];
#pragma unroll
        for (int i = 0; i < 16; i++)
            A[(eh * 16 + i) * 128 + c] = ssp(acc[i] + bias4);
    }
    __syncthreads();

    // v = A @ w5 + b5 ; out = x + v (x re-read from global)
#pragma unroll
    for (int i = 0; i < 16; i++) acc[i] = 0.f;
    for (int k = 0; k < 128; k += 4) {
        const float wa = w5[(k + 0) * CH + c];
        const float wb = w5[(k + 1) * CH + c];
        const float wc = w5[(k + 2) * CH + c];
        const float wd = w5[(k + 3) * CH + c];
#pragma unroll
        for (int i = 0; i < 16; i++) {
            const float4 v = *(const float4*)&A[(eh * 16 + i) * CH + k];
            acc[i] = fmaf(v.x, wa, acc[i]);
            acc[i] = fmaf(v.y, wb, acc[i]);
            acc[i] = fmaf(v.z, wc, acc[i]);
            acc[i] = fmaf(v.w, wd, acc[i]);
        }
    }
    {
        const float bias5 = b5[c];
#pragma unroll
        for (int i = 0; i < 16; i++) {
            const int r = eh * 16 + i;
            if (r < rows) {
                const size_t off = ((size_t)(n0 + r)) * CH + c;
                out[off] = x[off] + acc[i] + bias5;
            }
        }
    }
}

// ---- node side, atomic fallback: f=x@w3; conv=convw*f; MLP ----
__global__ __launch_bounds__(256) void node_all(const float* __restrict__ x,
                                                const float* __restrict__ w3,
                                                const float* __restrict__ w4,
                                                const float* __restrict__ b4,
                                                const float* __restrict__ w5,
                                                const float* __restrict__ b5,
                                                const float* __restrict__ convw,
                                                float* __restrict__ out,
                                                int n_nodes) {
    __shared__ float A[32 * 128];
    __shared__ float B[32 * 128];
    const int t = threadIdx.x;
    const int n0 = blockIdx.x * 32;
    const int rows = min(32, n_nodes - n0);
    {
        const float4* g = (const float4*)(x + (size_t)n0 * CH);
        float4* s = (float4*)A;
        for (int i = t; i < rows * 32; i += 256) s[i] = g[i];
    }
    __syncthreads();
    const int c = t & 127, eh = t >> 7;
    float acc[16];
#pragma unroll
    for (int i = 0; i < 16; i++) acc[i] = 0.f;
    for (int k = 0; k < 128; k += 4) {
        const float wa = w3[(k + 0) * CH + c];
        const float wb = w3[(k + 1) * CH + c];
        const float wc = w3[(k + 2) * CH + c];
        const float wd = w3[(k + 3) * CH + c];
#pragma unroll
        for (int i = 0; i < 16; i++) {
            const float4 v = *(const float4*)&A[(eh * 16 + i) * CH + k];
            acc[i] = fmaf(v.x, wa, acc[i]);
            acc[i] = fmaf(v.y, wb, acc[i]);
            acc[i] = fmaf(v.z, wc, acc[i]);
            acc[i] = fmaf(v.w, wd, acc[i]);
        }
    }
#pragma unroll
    for (int i = 0; i < 16; i++) {
        const int r = eh * 16 + i;
        B[r * 128 + c] = (r < rows) ? acc[i] * convw[((size_t)(n0 + r)) * CH + c] : 0.f;
    }
    __syncthreads();
#pragma unroll
    for (int i = 0; i < 16; i++) acc[i] = 0.f;
    for (int k = 0; k < 128; k += 4) {
        const float wa = w4[(k + 0) * CH + c];
        const float wb = w4[(k + 1) * CH + c];
        const float wc = w4[(k + 2) * CH + c];
        const float wd = w4[(k + 3) * CH + c];
#pragma unroll
        for (int i = 0; i < 16; i++) {
            const float4 v = *(const float4*)&B[(eh * 16 + i) * CH + k];
            acc[i] = fmaf(v.x, wa, acc[i]);
            acc[i] = fmaf(v.y, wb, acc[i]);
            acc[i] = fmaf(v.z, wc, acc[i]);
            acc[i] = fmaf(v.w, wd, acc[i]);
        }
    }
    {
        const float bias4 = b4[c];
#pragma unroll
        for (int i = 0; i < 16; i++)
            A[(eh * 16 + i) * 128 + c] = ssp(acc[i] + bias4);
    }
    __syncthreads();
#pragma unroll
    for (int i = 0; i < 16; i++) acc[i] = 0.f;
    for (int k = 0; k < 128; k += 4) {
        const float wa = w5[(k + 0) * CH + c];
        const float wb = w5[(k + 1) * CH + c];
        const float wc = w5[(k + 2) * CH + c];
        const float wd = w5[(k + 3) * CH + c];
#pragma unroll
        for (int i = 0; i < 16; i++) {
            const float4 v = *(const float4*)&A[(eh * 16 + i) * CH + k];
            acc[i] = fmaf(v.x, wa, acc[i]);
            acc[i] = fmaf(v.y, wb, acc[i]);
            acc[i] = fmaf(v.z, wc, acc[i]);
            acc[i] = fmaf(v.w, wd, acc[i]);
        }
    }
    {
        const float bias5 = b5[c];
#pragma unroll
        for (int i = 0; i < 16; i++) {
            const int r = eh * 16 + i;
            if (r < rows) {
                const size_t off = ((size_t)(n0 + r)) * CH + c;
                out[off] = x[off] + acc[i] + bias5;
            }
        }
    }
}

static inline size_t align_up(size_t v, size_t a) { return (v + a - 1) & ~(a - 1); }

extern "C" void kernel_launch(void* const* d_in, const int* in_sizes, int n_in,
                              void* d_out, int out_size, void* d_ws, size_t ws_size,
                              hipStream_t stream) {
    const float* rbf = (const float*)d_in[0];
    const float* x   = (const float*)d_in[1];
    const int*   src = (const int*)d_in[2];
    const float* w1  = (const float*)d_in[3];
    const float* b1  = (const float*)d_in[4];
    const float* w2  = (const float*)d_in[5];
    const float* b2  = (const float*)d_in[6];
    const float* w3  = (const float*)d_in[7];
    const float* w4  = (const float*)d_in[8];
    const float* b4  = (const float*)d_in[9];
    const float* w5  = (const float*)d_in[10];
    const float* b5  = (const float*)d_in[11];

    float* out = (float*)d_out;
    const size_t wElems = 128 * K1P + 128 * 128;      // 45056 bf16

    // ---- gather-path ws layout ----
    size_t off = 0;
    const size_t o_wbuf = off;            off = align_up(off + (size_t)NEDGES * CH * 2, 256);
    const size_t o_eidx = off;            off = align_up(off + (size_t)NEDGES * 4, 256);
    const size_t o_csr  = off;            off = align_up(off + (size_t)(NNODES + 1) * 4, 256);
    const size_t o_cur  = off;            off = align_up(off + (size_t)NNODES * 4, 256);
    const size_t o_wT   = off;            off = align_up(off + wElems * 2, 256);
    const size_t needG  = off;

    if (ws_size >= needG) {
        unsigned short* wbuf = (unsigned short*)((char*)d_ws + o_wbuf);
        int* eidx            = (int*)((char*)d_ws + o_eidx);
        int* csr_off         = (int*)((char*)d_ws + o_csr);
        int* cur             = (int*)((char*)d_ws + o_cur);
        unsigned short* w1T  = (unsigned short*)((char*)d_ws + o_wT);
        unsigned short* w2T  = w1T + 128 * K1P;

        hipMemsetAsync(cur, 0, (size_t)NNODES * 4, stream);
        prep_weights<<<(int)((wElems + 255) / 256), 256, 0, stream>>>(w1, w2, w1T, w2T);
        edge_kernel<0><<<NEDGES / 64, 256, 0, stream>>>(rbf, b1, b2, src, w1T, w2T, wbuf, nullptr);
        k_hist<<<(NEDGES + 255) / 256, 256, 0, stream>>>(src, cur);
        k_scan<<<1, 256, 0, stream>>>(cur, csr_off);
        k_fill<<<(NEDGES + 255) / 256, 256, 0, stream>>>(src, cur, eidx);
        node_gather<<<(NNODES + 31) / 32, 256, 0, stream>>>(x, w3, w4, b4, w5, b5,
                                                            wbuf, eidx, csr_off, out, NNODES);
    } else {
        // ---- atomic fallback (R2 path) ----
        float* convw = (float*)d_ws;
        const size_t convBytes = (size_t)NNODES * CH * sizeof(float);
        unsigned short* w1T;
        if (ws_size >= convBytes + wElems * 2)
            w1T = (unsigned short*)((char*)d_ws + convBytes);
        else
            w1T = (unsigned short*)d_out;
        unsigned short* w2T = w1T + 128 * K1P;

        hipMemsetAsync(convw, 0, convBytes, stream);
        prep_weights<<<(int)((wElems + 255) / 256), 256, 0, stream>>>(w1, w2, w1T, w2T);
        edge_kernel<1><<<NEDGES / 64, 256, 0, stream>>>(rbf, b1, b2, src, w1T, w2T, nullptr, convw);
        node_all<<<(NNODES + 31) / 32, 256, 0, stream>>>(x, w3, w4, b4, w5, b5, convw, out, NNODES);
    }
}

// Round 4
// 593.029 us; speedup vs baseline: 1.2136x; 1.2136x over previous
//
#include <hip/hip_runtime.h>

#define CH      128
#define RBFD    200
#define NNODES  50000
#define NEDGES  600000
#define LOG2F_  0.6931471805599453f
#define K1P     224     // w1T rows padded to 224 (7 k-tiles of 32)

typedef __attribute__((ext_vector_type(8))) __bf16 bf16x8;
typedef __attribute__((ext_vector_type(4))) float  f32x4;

__device__ __forceinline__ float ssp(float x) {
    float sp = (x < 14.0f) ? __logf(1.0f + __expf(x)) : x;
    return sp - LOG2F_;
}

__device__ __forceinline__ unsigned short f2bf(float f) {
    union { float f; unsigned int u; } v; v.f = f;
    unsigned int r = v.u + 0x7FFFu + ((v.u >> 16) & 1u);   // RNE
    return (unsigned short)(r >> 16);
}

__device__ __forceinline__ float bf2f(unsigned short s) {
    union { unsigned int u; float f; } v; v.u = ((unsigned int)s) << 16;
    return v.f;
}

// 8 consecutive fp32 -> bf16x8 via v_cvt_pk_bf16_f32 (dst.lo = src0, dst.hi = src1)
__device__ __forceinline__ bf16x8 load_cvt8(const float* p) {
    float4 f0 = *(const float4*)p;
    float4 f1 = *(const float4*)(p + 4);
    union { unsigned int u[4]; bf16x8 v; } r;
    asm("v_cvt_pk_bf16_f32 %0, %1, %2" : "=v"(r.u[0]) : "v"(f0.x), "v"(f0.y));
    asm("v_cvt_pk_bf16_f32 %0, %1, %2" : "=v"(r.u[1]) : "v"(f0.z), "v"(f0.w));
    asm("v_cvt_pk_bf16_f32 %0, %1, %2" : "=v"(r.u[2]) : "v"(f1.x), "v"(f1.y));
    asm("v_cvt_pk_bf16_f32 %0, %1, %2" : "=v"(r.u[3]) : "v"(f1.z), "v"(f1.w));
    return r.v;
}

// ---- prep: bf16-transposed weights w1T[128][224] (zero-padded), w2T[128][128] ----
__global__ __launch_bounds__(256) void prep_weights(const float* __restrict__ w1,
                                                    const float* __restrict__ w2,
                                                    unsigned short* __restrict__ w1T,
                                                    unsigned short* __restrict__ w2T) {
    int i = blockIdx.x * 256 + threadIdx.x;
    if (i < 128 * K1P) {
        int n = i / K1P, k = i % K1P;
        w1T[i] = (k < RBFD) ? f2bf(w1[k * CH + n]) : (unsigned short)0;
    } else {
        int j = i - 128 * K1P;
        if (j < 128 * 128) {
            int n = j / 128, k = j % 128;
            w2T[j] = f2bf(w2[k * CH + n]);
        }
    }
}

// ---- CSR build (parallel scan) ----
__global__ __launch_bounds__(256) void k_hist(const int* __restrict__ src, int* __restrict__ cur) {
    int e = blockIdx.x * 256 + threadIdx.x;
    if (e < NEDGES) atomicAdd(&cur[src[e]], 1);
}

__global__ __launch_bounds__(256) void k_scan1(const int* __restrict__ cur, int* __restrict__ bsum) {
    __shared__ int s[256];
    const int t = threadIdx.x;
    int i = blockIdx.x * 256 + t;
    s[t] = (i < NNODES) ? cur[i] : 0;
    __syncthreads();
    for (int d = 128; d > 0; d >>= 1) {
        if (t < d) s[t] += s[t + d];
        __syncthreads();
    }
    if (t == 0) bsum[blockIdx.x] = s[0];
}

__global__ __launch_bounds__(256) void k_scan2(const int* __restrict__ bsum, int* __restrict__ bpre) {
    __shared__ int s[256];
    const int t = threadIdx.x;
    int v0 = (t < 196) ? bsum[t] : 0;
    s[t] = v0;
    __syncthreads();
    for (int d = 1; d < 256; d <<= 1) {
        int v = (t >= d) ? s[t - d] : 0;
        __syncthreads();
        s[t] += v;
        __syncthreads();
    }
    if (t < 196) bpre[t] = s[t] - v0;   // exclusive
}

__global__ __launch_bounds__(256) void k_scan3(const int* __restrict__ deg_in,
                                               const int* __restrict__ bpre,
                                               int* __restrict__ csr_off,
                                               int* __restrict__ cur) {
    __shared__ int s[256];
    const int t = threadIdx.x, b = blockIdx.x;
    const int i = b * 256 + t;
    int d0 = (i < NNODES) ? deg_in[i] : 0;
    s[t] = d0;
    __syncthreads();
    for (int d = 1; d < 256; d <<= 1) {
        int v = (t >= d) ? s[t - d] : 0;
        __syncthreads();
        s[t] += v;
        __syncthreads();
    }
    if (i < NNODES) {
        int ex = bpre[b] + s[t] - d0;
        csr_off[i] = ex;
        cur[i] = ex;
    }
    if (i == NNODES - 1) csr_off[NNODES] = NEDGES;
}

__global__ __launch_bounds__(256) void k_fill(const int* __restrict__ src,
                                              int* __restrict__ cur,
                                              int* __restrict__ eidx) {
    int e = blockIdx.x * 256 + threadIdx.x;
    if (e < NEDGES) {
        int pos = atomicAdd(&cur[src[e]], 1);
        eidx[pos] = e;
    }
}

// ---- edge pipeline, barrier-free: each wave owns 16 edges x 128 cols.
//      w = ssp(ssp(rbf@w1+b1)@w2+b2) -> wbuf[E][128] bf16 (streaming) ----
__global__ __launch_bounds__(256, 4) void edge_kernel2(const float* __restrict__ rbf,
                                                       const float* __restrict__ b1v,
                                                       const float* __restrict__ b2v,
                                                       const unsigned short* __restrict__ w1T,
                                                       const unsigned short* __restrict__ w2T,
                                                       unsigned short* __restrict__ wbuf) {
    __shared__ unsigned short tile[4][16 * 128];   // 4 KB per wave, XOR-swizzled rows
    const int t = threadIdx.x;
    const int lane = t & 63;
    const int wv = t >> 6;
    const int l15 = lane & 15;
    const int lg  = lane >> 4;                     // k-group 0..3
    const size_t erow0 = (size_t)blockIdx.x * 64 + (size_t)wv * 16;
    unsigned short* my = tile[wv];
    char* myb = (char*)my;

    // ---- A1 fragments direct from global: row erow0+l15, k = kt*32+lg*8 ----
    bf16x8 a1[7];
    const float* arow = rbf + (erow0 + l15) * RBFD;
#pragma unroll
    for (int kt = 0; kt < 6; kt++)
        a1[kt] = load_cvt8(arow + kt * 32 + lg * 8);
    if (lg == 0) {
        a1[6] = load_cvt8(arow + 192);             // k 192..199
    } else {
        union { unsigned int u[4]; bf16x8 v; } z;
        z.u[0] = z.u[1] = z.u[2] = z.u[3] = 0;
        a1[6] = z.v;                               // k >= 200 zero-pad
    }

    const int myrow0 = lg * 4;                     // C/D: row=(lane>>4)*4+r, col=l15 (+16*nt)

    // ---- GEMM1: h = ssp(rbf @ w1 + b1) -> swizzled LDS (bf16) ----
#pragma unroll
    for (int nt = 0; nt < 8; nt++) {
        f32x4 acc = {0.f, 0.f, 0.f, 0.f};
        const unsigned short* bbase = w1T + (size_t)(nt * 16 + l15) * K1P + lg * 8;
#pragma unroll
        for (int kt = 0; kt < 7; kt++) {
            bf16x8 b = *(const bf16x8*)(bbase + kt * 32);
            acc = __builtin_amdgcn_mfma_f32_16x16x32_bf16(a1[kt], b, acc, 0, 0, 0);
        }
        const float bias = b1v[nt * 16 + l15];
#pragma unroll
        for (int r = 0; r < 4; r++) {
            const int row = myrow0 + r;
            const int colb = (nt * 32 + l15 * 2) ^ ((row & 7) << 4);
            *(unsigned short*)(myb + row * 256 + colb) = f2bf(ssp(acc[r] + bias));
        }
    }

    // ---- A2 fragments from swizzled LDS: row = l15, k-bytes = kt*64+lg*16 ----
    bf16x8 a2[4];
#pragma unroll
    for (int kt = 0; kt < 4; kt++) {
        const int boff = l15 * 256 + ((kt * 64 + lg * 16) ^ ((l15 & 7) << 4));
        a2[kt] = *(const bf16x8*)(myb + boff);
    }

    // ---- GEMM2: w = ssp(h @ w2 + b2) -> same swizzled LDS (h dead) ----
#pragma unroll
    for (int nt = 0; nt < 8; nt++) {
        f32x4 acc = {0.f, 0.f, 0.f, 0.f};
        const unsigned short* bbase = w2T + (size_t)(nt * 16 + l15) * 128 + lg * 8;
#pragma unroll
        for (int kt = 0; kt < 4; kt++) {
            bf16x8 b = *(const bf16x8*)(bbase + kt * 32);
            acc = __builtin_amdgcn_mfma_f32_16x16x32_bf16(a2[kt], b, acc, 0, 0, 0);
        }
        const float bias = b2v[nt * 16 + l15];
#pragma unroll
        for (int r = 0; r < 4; r++) {
            const int row = myrow0 + r;
            const int colb = (nt * 32 + l15 * 2) ^ ((row & 7) << 4);
            *(unsigned short*)(myb + row * 256 + colb) = f2bf(ssp(acc[r] + bias));
        }
    }

    // ---- copy-out: lane covers 64 B of one row; wave writes 16 rows x 256 B ----
    {
        const int row = lane >> 2, q = lane & 3;
        float4 o[4];
#pragma unroll
        for (int j = 0; j < 4; j++) {
            const int boff = row * 256 + ((q * 64 + j * 16) ^ ((row & 7) << 4));
            o[j] = *(const float4*)(myb + boff);
        }
        float4* gdst = (float4*)((char*)wbuf + (erow0 + row) * 256 + q * 64);
#pragma unroll
        for (int j = 0; j < 4; j++) gdst[j] = o[j];
    }
}

// ---- node side: f=x@w3 (fp32); conv = f * gather-sum(wbuf); y=ssp(conv@w4+b4);
//      out = x + y@w5 + b5.  Gather is wave-per-node, fully coalesced ----
__global__ __launch_bounds__(256) void node_gather2(const float* __restrict__ x,
                                                    const float* __restrict__ w3,
                                                    const float* __restrict__ w4,
                                                    const float* __restrict__ b4,
                                                    const float* __restrict__ w5,
                                                    const float* __restrict__ b5,
                                                    const unsigned short* __restrict__ wbuf,
                                                    const int* __restrict__ eidx,
                                                    const int* __restrict__ csr_off,
                                                    float* __restrict__ out,
                                                    int n_nodes) {
    __shared__ float A[32 * 128];
    __shared__ float B[32 * 128];
    const int t = threadIdx.x;
    const int n0 = blockIdx.x * 32;
    const int rows = min(32, n_nodes - n0);

    {   // stage x tile
        const float4* g = (const float4*)(x + (size_t)n0 * CH);
        float4* s = (float4*)A;
        for (int i = t; i < rows * 32; i += 256) s[i] = g[i];
    }
    __syncthreads();

    const int c = t & 127, eh = t >> 7;
    float acc[16];

    // f = x @ w3 -> B
#pragma unroll
    for (int i = 0; i < 16; i++) acc[i] = 0.f;
    for (int k = 0; k < 128; k += 4) {
        const float wa = w3[(k + 0) * CH + c];
        const float wb = w3[(k + 1) * CH + c];
        const float wc = w3[(k + 2) * CH + c];
        const float wd = w3[(k + 3) * CH + c];
#pragma unroll
        for (int i = 0; i < 16; i++) {
            const float4 v = *(const float4*)&A[(eh * 16 + i) * CH + k];
            acc[i] = fmaf(v.x, wa, acc[i]);
            acc[i] = fmaf(v.y, wb, acc[i]);
            acc[i] = fmaf(v.z, wc, acc[i]);
            acc[i] = fmaf(v.w, wd, acc[i]);
        }
    }
#pragma unroll
    for (int i = 0; i < 16; i++) B[(eh * 16 + i) * 128 + c] = acc[i];
    __syncthreads();

    // ---- gather: wave wv handles nodes [wv*8, wv*8+8); lane covers ch 2l,2l+1 ----
    {
        const int lane = t & 63, wv = t >> 6;
        const int c0 = lane * 2;
        for (int rr = 0; rr < 8; rr++) {
            const int r = wv * 8 + rr;
            const int n = n0 + r;
            float s0 = 0.f, s1 = 0.f;
            if (n < n_nodes) {
                const int o0 = csr_off[n], o1 = csr_off[n + 1];
                int j = o0;
                for (; j + 3 < o1; j += 4) {
                    const int ea = eidx[j], eb = eidx[j + 1], ec = eidx[j + 2], ed = eidx[j + 3];
                    const unsigned ua = *(const unsigned*)(wbuf + (size_t)ea * CH + c0);
                    const unsigned ub = *(const unsigned*)(wbuf + (size_t)eb * CH + c0);
                    const unsigned uc = *(const unsigned*)(wbuf + (size_t)ec * CH + c0);
                    const unsigned ud = *(const unsigned*)(wbuf + (size_t)ed * CH + c0);
                    s0 += bf2f((unsigned short)ua) + bf2f((unsigned short)ub)
                        + bf2f((unsigned short)uc) + bf2f((unsigned short)ud);
                    s1 += bf2f((unsigned short)(ua >> 16)) + bf2f((unsigned short)(ub >> 16))
                        + bf2f((unsigned short)(uc >> 16)) + bf2f((unsigned short)(ud >> 16));
                }
                for (; j < o1; j++) {
                    const unsigned ua = *(const unsigned*)(wbuf + (size_t)eidx[j] * CH + c0);
                    s0 += bf2f((unsigned short)ua);
                    s1 += bf2f((unsigned short)(ua >> 16));
                }
            }
            const float2 f2 = *(const float2*)&B[r * 128 + c0];
            float2 v2;
            v2.x = (n < n_nodes) ? f2.x * s0 : 0.f;
            v2.y = (n < n_nodes) ? f2.y * s1 : 0.f;
            *(float2*)&B[r * 128 + c0] = v2;
        }
    }
    __syncthreads();

    // y = ssp(B @ w4 + b4) -> A
#pragma unroll
    for (int i = 0; i < 16; i++) acc[i] = 0.f;
    for (int k = 0; k < 128; k += 4) {
        const float wa = w4[(k + 0) * CH + c];
        const float wb = w4[(k + 1) * CH + c];
        const float wc = w4[(k + 2) * CH + c];
        const float wd = w4[(k + 3) * CH + c];
#pragma unroll
        for (int i = 0; i < 16; i++) {
            const float4 v = *(const float4*)&B[(eh * 16 + i) * CH + k];
            acc[i] = fmaf(v.x, wa, acc[i]);
            acc[i] = fmaf(v.y, wb, acc[i]);
            acc[i] = fmaf(v.z, wc, acc[i]);
            acc[i] = fmaf(v.w, wd, acc[i]);
        }
    }
    {
        const float bias4 = b4[c];
#pragma unroll
        for (int i = 0; i < 16; i++)
            A[(eh * 16 + i) * 128 + c] = ssp(acc[i] + bias4);
    }
    __syncthreads();

    // v = A @ w5 + b5 ; out = x + v
#pragma unroll
    for (int i = 0; i < 16; i++) acc[i] = 0.f;
    for (int k = 0; k < 128; k += 4) {
        const float wa = w5[(k + 0) * CH + c];
        const float wb = w5[(k + 1) * CH + c];
        const float wc = w5[(k + 2) * CH + c];
        const float wd = w5[(k + 3) * CH + c];
#pragma unroll
        for (int i = 0; i < 16; i++) {
            const float4 v = *(const float4*)&A[(eh * 16 + i) * CH + k];
            acc[i] = fmaf(v.x, wa, acc[i]);
            acc[i] = fmaf(v.y, wb, acc[i]);
            acc[i] = fmaf(v.z, wc, acc[i]);
            acc[i] = fmaf(v.w, wd, acc[i]);
        }
    }
    {
        const float bias5 = b5[c];
#pragma unroll
        for (int i = 0; i < 16; i++) {
            const int r = eh * 16 + i;
            if (r < rows) {
                const size_t off = ((size_t)(n0 + r)) * CH + c;
                out[off] = x[off] + acc[i] + bias5;
            }
        }
    }
}

static inline size_t align_up(size_t v, size_t a) { return (v + a - 1) & ~(a - 1); }

extern "C" void kernel_launch(void* const* d_in, const int* in_sizes, int n_in,
                              void* d_out, int out_size, void* d_ws, size_t ws_size,
                              hipStream_t stream) {
    const float* rbf = (const float*)d_in[0];
    const float* x   = (const float*)d_in[1];
    const int*   src = (const int*)d_in[2];
    const float* w1  = (const float*)d_in[3];
    const float* b1  = (const float*)d_in[4];
    const float* w2  = (const float*)d_in[5];
    const float* b2  = (const float*)d_in[6];
    const float* w3  = (const float*)d_in[7];
    const float* w4  = (const float*)d_in[8];
    const float* b4  = (const float*)d_in[9];
    const float* w5  = (const float*)d_in[10];
    const float* b5  = (const float*)d_in[11];

    float* out = (float*)d_out;
    const size_t wElems = 128 * K1P + 128 * 128;   // 45056 bf16

    size_t off = 0;
    const size_t o_wbuf = off;  off = align_up(off + (size_t)NEDGES * CH * 2, 256);
    const size_t o_eidx = off;  off = align_up(off + (size_t)NEDGES * 4, 256);
    const size_t o_csr  = off;  off = align_up(off + (size_t)(NNODES + 1) * 4, 256);
    const size_t o_cur  = off;  off = align_up(off + (size_t)NNODES * 4, 256);
    const size_t o_bs   = off;  off = align_up(off + 256 * 4, 256);
    const size_t o_bp   = off;  off = align_up(off + 256 * 4, 256);
    const size_t o_wT   = off;  off = align_up(off + wElems * 2, 256);

    unsigned short* wbuf = (unsigned short*)((char*)d_ws + o_wbuf);
    int* eidx            = (int*)((char*)d_ws + o_eidx);
    int* csr_off         = (int*)((char*)d_ws + o_csr);
    int* cur             = (int*)((char*)d_ws + o_cur);
    int* bsum            = (int*)((char*)d_ws + o_bs);
    int* bpre            = (int*)((char*)d_ws + o_bp);
    unsigned short* w1T  = (unsigned short*)((char*)d_ws + o_wT);
    unsigned short* w2T  = w1T + 128 * K1P;

    hipMemsetAsync(cur, 0, (size_t)NNODES * 4, stream);
    prep_weights<<<(int)((wElems + 255) / 256), 256, 0, stream>>>(w1, w2, w1T, w2T);
    edge_kernel2<<<NEDGES / 64, 256, 0, stream>>>(rbf, b1, b2, w1T, w2T, wbuf);
    k_hist<<<(NEDGES + 255) / 256, 256, 0, stream>>>(src, cur);
    k_scan1<<<196, 256, 0, stream>>>(cur, bsum);
    k_scan2<<<1, 256, 0, stream>>>(bsum, bpre);
    k_scan3<<<196, 256, 0, stream>>>(cur, bpre, csr_off, cur);
    k_fill<<<(NEDGES + 255) / 256, 256, 0, stream>>>(src, cur, eidx);
    node_gather2<<<(NNODES + 31) / 32, 256, 0, stream>>>(x, w3, w4, b4, w5, b5,
                                                         wbuf, eidx, csr_off, out, NNODES);
}